// Round 2
// baseline (237.812 us; speedup 1.0000x reference)
//
#include <hip/hip_runtime.h>
#include <stdint.h>

#define BB 8
#define TT 256
#define DD 256
#define NSTEP 12
#define NNEG 100
#define SLOTP 104   // padded slots (1 positive + 100 negatives + 3 pad), uint16 rows

typedef _Float16 f16x8 __attribute__((ext_vector_type(8)));
typedef float f32x4 __attribute__((ext_vector_type(4)));

// ---------------- f32 -> OCP e4m3fn ----------------
__device__ __forceinline__ uint32_t f32_to_e4m3(float x) {
#if __has_builtin(__builtin_amdgcn_cvt_pk_fp8_f32)
  return (uint32_t)__builtin_amdgcn_cvt_pk_fp8_f32(x, x, 0, false) & 0xFFu;
#else
  union { float f; uint32_t u; } c; c.f = x;
  uint32_t s = (c.u >> 24) & 0x80u;
  float a = fabsf(x);
  if (!(a < 448.f)) return s | 0x7Eu;
  int e; float mf = frexpf(a, &e); (void)mf;
  e -= 1;
  int E = e < -6 ? -6 : e;
  float q = nearbyintf(ldexpf(a, 3 - E));
  int qi = (int)q;
  if (qi == 0) return s;
  while (qi >= 16) { qi >>= 1; ++E; }
  if (qi < 8) return s | (uint32_t)qi;                       // subnormal (E==-6)
  return s | ((uint32_t)(E + 7) << 3) | (uint32_t)(qi & 7);
#endif
}

__device__ __forceinline__ uint32_t f32x4_to_e4m3x4(float x, float y, float z, float w) {
#if __has_builtin(__builtin_amdgcn_cvt_pk_fp8_f32)
  int lo = __builtin_amdgcn_cvt_pk_fp8_f32(x, y, 0, false);
  return (uint32_t)__builtin_amdgcn_cvt_pk_fp8_f32(z, w, lo, true);
#else
  return f32_to_e4m3(x) | (f32_to_e4m3(y) << 8) | (f32_to_e4m3(z) << 16) | (f32_to_e4m3(w) << 24);
#endif
}

__device__ __forceinline__ long pk64(uint2 v) {
  union { uint2 u; long l; } c; c.u = v; return c.l;
}

// ---------------- Threefry2x32 (JAX-compatible), host+device ----------------
__host__ __device__ __forceinline__ void tf2x32(uint32_t k0, uint32_t k1,
                                                uint32_t x0, uint32_t x1,
                                                uint32_t &y0, uint32_t &y1) {
  const uint32_t ks2 = k0 ^ k1 ^ 0x1BD11BDAu;
  x0 += k0; x1 += k1;
#define TF_R(r) { x0 += x1; x1 = (x1 << (r)) | (x1 >> (32 - (r))); x1 ^= x0; }
  TF_R(13) TF_R(15) TF_R(26) TF_R(6)
  x0 += k1; x1 += ks2 + 1u;
  TF_R(17) TF_R(29) TF_R(16) TF_R(24)
  x0 += ks2; x1 += k0 + 2u;
  TF_R(13) TF_R(15) TF_R(26) TF_R(6)
  x0 += k0; x1 += k1 + 3u;
  TF_R(17) TF_R(29) TF_R(16) TF_R(24)
  x0 += k1; x1 += ks2 + 4u;
  TF_R(13) TF_R(15) TF_R(26) TF_R(6)
  x0 += ks2; x1 += k0 + 5u;
#undef TF_R
  y0 = x0; y1 = x1;
}

// ---------------- host-computed per-step constants ----------------
struct IdxParams {
  uint32_t k1x[NSTEP], k1y[NSTEP], k2x[NSTEP], k2y[NSTEP];
  uint32_t mult[NSTEP];
  uint32_t Msp[NSTEP], Ssp[NSTEP], Asp[NSTEP];   // magic for span = 8*T2
  uint32_t Mt2[NSTEP], St2[NSTEP], At2[NSTEP];   // magic for T2
};

// Hacker's Delight 10-9 unsigned magic
static void magicu(uint32_t d, uint32_t* M, uint32_t* s, uint32_t* a) {
  uint32_t p, nc, delta, q1, r1, q2, r2;
  *a = 0;
  nc = 0xFFFFFFFFu - (0u - d) % d;
  p = 31;
  q1 = 0x80000000u / nc; r1 = 0x80000000u - q1 * nc;
  q2 = 0x7FFFFFFFu / d;  r2 = 0x7FFFFFFFu - q2 * d;
  do {
    p = p + 1;
    if (r1 >= nc - r1) { q1 = 2*q1 + 1; r1 = 2*r1 - nc; }
    else               { q1 = 2*q1;     r1 = 2*r1; }
    if (r2 + 1 >= d - r2) {
      if (q2 >= 0x7FFFFFFFu) *a = 1;
      q2 = 2*q2 + 1; r2 = 2*r2 + 1 - d;
    } else {
      if (q2 >= 0x80000000u) *a = 1;
      q2 = 2*q2; r2 = 2*r2 + 1;
    }
    delta = d - 1 - r2;
  } while (p < 64 && (q1 < delta || (q1 == delta && r1 == 0)));
  *M = q2 + 1; *s = p - 32;
}

__device__ __forceinline__ uint32_t mdiv(uint32_t n, uint32_t M, uint32_t s, uint32_t a) {
  uint32_t q = __umulhi(n, M);
  if (a) { q = ((n - q) >> 1) + q; return q >> (s - 1); }
  return q >> s;
}

// ------------- prep: tgt-l2norm->e4m3, ctx->f16, W->f16, idx table, zero out -------------
// blocks [0,512): targets; [512,1024): ctx; [1024,1792): W; [1792,1792+9984): index table.
__global__ __launch_bounds__(256) void prep_kernel(const IdxParams P,
                                                   const float* __restrict__ tgt,
                                                   const float* __restrict__ ctx,
                                                   const float* __restrict__ W,
                                                   uint8_t* __restrict__ tn8,
                                                   _Float16* __restrict__ ctxh,
                                                   _Float16* __restrict__ Wh,
                                                   uint16_t* __restrict__ idxTab,
                                                   float* __restrict__ out) {
  const int bx = blockIdx.x;
  const int tid = threadIdx.x;
  if (bx == 0 && tid == 0) out[0] = 0.f;
  if (bx < 512) {                                        // tgt: normalize -> e4m3
    const int lane = tid & 63;
    const int row = bx * 4 + (tid >> 6);
    float4 v = ((const float4*)(tgt + (size_t)row * DD))[lane];
    float ss = v.x*v.x + v.y*v.y + v.z*v.z + v.w*v.w;
#pragma unroll
    for (int off = 1; off < 64; off <<= 1) ss += __shfl_xor(ss, off, 64);
    const float sc = 1.0f / fmaxf(sqrtf(ss), 1e-12f);
    ((uint32_t*)(tn8 + (size_t)row * DD))[lane] =
        f32x4_to_e4m3x4(v.x * sc, v.y * sc, v.z * sc, v.w * sc);
  } else if (bx < 1792) {
    const int lane = tid & 63;
    union { _Float16 h[4]; uint2 u; } o;
    if (bx < 1024) {                                     // ctx: plain convert
      const int row = (bx - 512) * 4 + (tid >> 6);
      float4 v = ((const float4*)(ctx + (size_t)row * DD))[lane];
      o.h[0] = (_Float16)v.x; o.h[1] = (_Float16)v.y;
      o.h[2] = (_Float16)v.z; o.h[3] = (_Float16)v.w;
      ((uint2*)(ctxh + (size_t)row * DD))[lane] = o.u;
    } else {                                             // W: plain convert (3072 rows)
      const int row = (bx - 1024) * 4 + (tid >> 6);
      float4 v = ((const float4*)(W + (size_t)row * DD))[lane];
      o.h[0] = (_Float16)v.x; o.h[1] = (_Float16)v.y;
      o.h[2] = (_Float16)v.z; o.h[3] = (_Float16)v.w;
      ((uint2*)(Wh + (size_t)row * DD))[lane] = o.u;
    }
  } else {                                               // index table: 832 blocks per step
    const int ib = bx - 1792;                            // 0..9983
    const int si = ib / 832;                             // block-uniform -> scalar P loads
    const int step = si + 1;
    const uint32_t T2 = (uint32_t)(TT - step);
    const uint32_t nloc = (uint32_t)(ib - si * 832) * 256u + (uint32_t)tid;  // 0..212991
    const uint32_t m = nloc / 104u;                      // b*256 + t
    const uint32_t slot = nloc - m * 104u;
    const uint32_t t = m & 255u;
    const uint32_t b = m >> 8;
    uint32_t v = 0u;
    if (t < T2 && slot <= (uint32_t)NNEG) {
      if (slot == 0u) {
        v = b * TT + t + (uint32_t)step;                 // positive row
      } else {
        const uint32_t j = (b * T2 + t) * NNEG + (slot - 1u);
        uint32_t h0, h1, l0, l1;
        tf2x32(P.k1x[si], P.k1y[si], 0u, j, h0, h1);
        tf2x32(P.k2x[si], P.k2y[si], 0u, j, l0, l1);
        const uint32_t span = 8u * T2;
        const uint32_t Msp = P.Msp[si], Ssp = P.Ssp[si], Asp = P.Asp[si];
        const uint32_t hm = h0 - mdiv(h0, Msp, Ssp, Asp) * span;
        const uint32_t lm = l0 - mdiv(l0, Msp, Ssp, Asp) * span;
        const uint32_t off = hm * P.mult[si] + lm;
        const uint32_t om = off - mdiv(off, Msp, Ssp, Asp) * span;
        const uint32_t bbq = mdiv(om, P.Mt2[si], P.St2[si], P.At2[si]);
        const uint32_t tt = om - bbq * T2;
        v = bbq * TT + tt + (uint32_t)step;
      }
    }
    idxTab[(size_t)si * (2048u * 104u) + nloc] = (uint16_t)v;
  }
}

// ------------- query GEMM (MFMA f16) + bias + l2norm -> e4m3 -------------
// grid (64 m-tiles of 32 rows, 12 steps), block 256 = 4 waves.
__global__ __launch_bounds__(256) void qgemm_mfma_kernel(const _Float16* __restrict__ ctxh,
                                                         const _Float16* __restrict__ Wh,
                                                         const float* __restrict__ bias,
                                                         uint8_t* __restrict__ qn8) {
  const int mt  = blockIdx.x;           // 0..63
  const int s   = blockIdx.y;           // 0..11
  const int tid = threadIdx.x;
  const int w   = tid >> 6;
  const int lane = tid & 63;
  const int sl = lane & 15;
  const int q  = lane >> 4;
  const int m0 = mt * 32;

  const _Float16* Arow0 = ctxh + ((size_t)(m0 + sl)) * DD + q * 8;
  const _Float16* Arow1 = Arow0 + (size_t)16 * DD;
  const _Float16* Bbase = Wh + (size_t)s * DD * DD + ((size_t)(w * 64 + sl)) * DD + q * 8;

  f32x4 acc[2][4];
#pragma unroll
  for (int mi = 0; mi < 2; ++mi)
#pragma unroll
    for (int nt = 0; nt < 4; ++nt) acc[mi][nt] = f32x4{0, 0, 0, 0};

#pragma unroll
  for (int k0 = 0; k0 < 8; ++k0) {
    const f16x8 a0 = *(const f16x8*)(Arow0 + k0 * 32);
    const f16x8 a1 = *(const f16x8*)(Arow1 + k0 * 32);
#pragma unroll
    for (int nt = 0; nt < 4; ++nt) {
      const f16x8 b = *(const f16x8*)(Bbase + (size_t)nt * 16 * DD + k0 * 32);
      acc[0][nt] = __builtin_amdgcn_mfma_f32_16x16x32_f16(a0, b, acc[0][nt], 0, 0, 0);
      acc[1][nt] = __builtin_amdgcn_mfma_f32_16x16x32_f16(a1, b, acc[1][nt], 0, 0, 0);
    }
  }
  const float* bp = bias + (size_t)s * DD + w * 64 + sl;
  __shared__ float part[4][32];
#pragma unroll
  for (int mi = 0; mi < 2; ++mi) {
#pragma unroll
    for (int nt = 0; nt < 4; ++nt) {
      const float bv = bp[nt * 16];
#pragma unroll
      for (int r = 0; r < 4; ++r) acc[mi][nt][r] += bv;
    }
    float ss[4];
#pragma unroll
    for (int r = 0; r < 4; ++r) {
      float v = 0.f;
#pragma unroll
      for (int nt = 0; nt < 4; ++nt) v += acc[mi][nt][r] * acc[mi][nt][r];
      ss[r] = v;
    }
#pragma unroll
    for (int off = 1; off < 16; off <<= 1) {
#pragma unroll
      for (int r = 0; r < 4; ++r) ss[r] += __shfl_xor(ss[r], off, 64);
    }
    if (sl == 0) {
#pragma unroll
      for (int r = 0; r < 4; ++r) part[w][mi * 16 + q * 4 + r] = ss[r];
    }
  }
  __syncthreads();
#pragma unroll
  for (int mi = 0; mi < 2; ++mi) {
#pragma unroll
    for (int r = 0; r < 4; ++r) {
      const int row = q * 4 + r;
      const float tot = part[0][mi * 16 + row] + part[1][mi * 16 + row]
                      + part[2][mi * 16 + row] + part[3][mi * 16 + row];
      const float sc = 1.0f / fmaxf(sqrtf(tot), 1e-12f);
      uint8_t* outp = qn8 + (((size_t)s * (BB * TT)) + m0 + mi * 16 + row) * DD + w * 64 + sl;
#pragma unroll
      for (int nt = 0; nt < 4; ++nt)
        outp[nt * 16] = (uint8_t)f32_to_e4m3(acc[mi][nt][r] * sc);
    }
  }
}

// ------------- scoring: fp8 MFMA, 16 queries/block, diag extraction -------------
// grid (16 t-chunks, 8 b, 12 steps), block 256 = 4 waves; wave w owns slots w,w+4,...
__global__ __launch_bounds__(256) void score_kernel(const uint8_t* __restrict__ qn8,
                                                    const uint8_t* __restrict__ tn8,
                                                    const uint16_t* __restrict__ idxTab,
                                                    float* __restrict__ out) {
  const int tc = blockIdx.x;            // 0..15
  const int b  = blockIdx.y;            // 0..7
  const int si = blockIdx.z;            // 0..11
  const int step = si + 1;
  const int T2 = TT - step;
  const int t0 = tc * 16;
  const int tid = threadIdx.x;
  const int w   = tid >> 6;
  const int l   = tid & 63;
  const int q16 = l & 15;               // MFMA column = local query
  const int kh  = l >> 4;               // k-chunk

  __shared__ int   ridx[16][SLOTP];
  __shared__ float logit[16][105];
  __shared__ float bsum;
  if (tid == 0) bsum = 0.f;

  // stage 16 query rows x 104 uint16 indices (13 uint4 per row)
  const uint16_t* g16 = idxTab + (size_t)(((si * BB + b) * TT) + t0) * SLOTP;
  if (tid < 208) {
    const int r = tid / 13, c = tid % 13;
    uint4 v = *(const uint4*)(g16 + (size_t)r * SLOTP + c * 8);
    int* dst = &ridx[r][c * 8];
    dst[0] = (int)(v.x & 0xFFFFu); dst[1] = (int)(v.x >> 16);
    dst[2] = (int)(v.y & 0xFFFFu); dst[3] = (int)(v.y >> 16);
    dst[4] = (int)(v.z & 0xFFFFu); dst[5] = (int)(v.z >> 16);
    dst[6] = (int)(v.w & 0xFFFFu); dst[7] = (int)(v.w >> 16);
  }

  // preload B fragments: 8 bytes of query q16 per k-chunk, 8 K-steps
  const uint8_t* qrow = qn8 + ((size_t)(si * (BB * TT) + b * TT + t0 + q16)) * DD + kh * 8;
  uint2 qv[8];
#pragma unroll
  for (int kk = 0; kk < 8; ++kk) qv[kk] = *(const uint2*)(qrow + kk * 32);

  __syncthreads();

  const bool diag = (kh == (q16 >> 2));
  const int  rr   = l & 3;
#pragma unroll 2
  for (int slot = w; slot <= NNEG; slot += 4) {
    const int R = ridx[q16][slot];
    const uint8_t* kr = tn8 + (size_t)R * DD + kh * 8;
    uint2 av[8];
#pragma unroll
    for (int kk = 0; kk < 8; ++kk) av[kk] = *(const uint2*)(kr + kk * 32);
    f32x4 acc0 = {0, 0, 0, 0}, acc1 = {0, 0, 0, 0};
#pragma unroll
    for (int kk = 0; kk < 8; kk += 2) {
      acc0 = __builtin_amdgcn_mfma_f32_16x16x32_fp8_fp8(pk64(av[kk]),     pk64(qv[kk]),     acc0, 0, 0, 0);
      acc1 = __builtin_amdgcn_mfma_f32_16x16x32_fp8_fp8(pk64(av[kk + 1]), pk64(qv[kk + 1]), acc1, 0, 0, 0);
    }
    const float d0 = rr == 0 ? acc0[0] : rr == 1 ? acc0[1] : rr == 2 ? acc0[2] : acc0[3];
    const float d1 = rr == 0 ? acc1[0] : rr == 1 ? acc1[1] : rr == 2 ? acc1[2] : acc1[3];
    if (diag) logit[q16][slot] = (d0 + d1) * 10.0f;   // 1/TEMP
  }
  __syncthreads();

  // softmax: 8 lanes per query, 16 queries on tid<128
  if (tid < 128) {
    const int q = tid >> 3, i = tid & 7;
    const int t = t0 + q;
    if (t < T2) {
      float m = -1e30f;
      for (int k = i; k <= NNEG; k += 8) m = fmaxf(m, logit[q][k]);
      m = fmaxf(m, __shfl_xor(m, 1, 64));
      m = fmaxf(m, __shfl_xor(m, 2, 64));
      m = fmaxf(m, __shfl_xor(m, 4, 64));
      float e = 0.f;
      for (int k = i; k <= NNEG; k += 8) e += __expf(logit[q][k] - m);
      e += __shfl_xor(e, 1, 64);
      e += __shfl_xor(e, 2, 64);
      e += __shfl_xor(e, 4, 64);
      if (i == 0) {
        const float lse = m + logf(e);
        atomicAdd(&bsum, (lse - logit[q][0]) / (12.0f * (float)(BB * T2)));
      }
    }
  }
  __syncthreads();
  if (tid == 0) atomicAdd(out, bsum);
}

extern "C" void kernel_launch(void* const* d_in, const int* in_sizes, int n_in,
                              void* d_out, int out_size, void* d_ws, size_t ws_size,
                              hipStream_t stream) {
  const float* ctx  = (const float*)d_in[0];
  const float* tgt  = (const float*)d_in[1];
  const float* W    = (const float*)d_in[2];
  const float* bias = (const float*)d_in[3];
  float* out = (float*)d_out;

  uint8_t* tn8   = (uint8_t*)d_ws;                               // 512 KB
  _Float16* ctxh = (_Float16*)(tn8 + (size_t)BB * TT * DD);      // 1 MB
  _Float16* Wh   = ctxh + (size_t)BB * TT * DD;                  // 1.5 MB
  uint8_t* qn8   = (uint8_t*)(Wh + (size_t)NSTEP * DD * DD);     // 6.29 MB
  uint16_t* idxTab = (uint16_t*)(qn8 + (size_t)NSTEP * BB * TT * DD); // 4.88 MB

  // host-side per-step constants (deterministic; same every call)
  IdxParams P;
  for (int s = 0; s < NSTEP; ++s) {
    uint32_t a, b;
    tf2x32(0u, 1234u, 0u, (uint32_t)(s + 1), a, b);              // fold_in(key(1234), step)
    uint32_t h1a, h1b, h2a, h2b;
    tf2x32(a, b, 0u, 2u, h1a, h1b);                              // split -> k1
    tf2x32(a, b, 1u, 3u, h2a, h2b);                              // split -> k2
    P.k1x[s] = h1a; P.k1y[s] = h1b; P.k2x[s] = h2a; P.k2y[s] = h2b;
    const uint32_t T2 = (uint32_t)(TT - (s + 1));
    const uint32_t span = 8u * T2;
    uint32_t m = 65536u % span;
    P.mult[s] = (uint32_t)(((uint64_t)m * m) % span);
    magicu(span, &P.Msp[s], &P.Ssp[s], &P.Asp[s]);
    magicu(T2,   &P.Mt2[s], &P.St2[s], &P.At2[s]);
  }

  // idx blocks: 12 steps x 832 blocks (= 8*256*104/256 entries each)
  hipLaunchKernelGGL(prep_kernel, dim3(1792 + 12 * 832), dim3(256), 0, stream,
                     P, tgt, ctx, W, tn8, ctxh, Wh, idxTab, out);
  hipLaunchKernelGGL(qgemm_mfma_kernel, dim3(64, NSTEP), dim3(256), 0, stream,
                     ctxh, Wh, bias, qn8);
  hipLaunchKernelGGL(score_kernel, dim3(16, BB, NSTEP), dim3(256), 0, stream,
                     qn8, tn8, idxTab, out);
}

// Round 3
// 166.325 us; speedup vs baseline: 1.4298x; 1.4298x over previous
//
#include <hip/hip_runtime.h>
#include <stdint.h>

#define BB 8
#define TT 256
#define DD 256
#define NSTEP 12
#define NNEG 100
#define SLOTP 104   // padded slots (1 positive + 100 negatives + 3 pad), uint16 rows

typedef _Float16 f16x8 __attribute__((ext_vector_type(8)));
typedef float f32x4 __attribute__((ext_vector_type(4)));

// ---------------- f32 -> OCP e4m3fn ----------------
__device__ __forceinline__ uint32_t f32_to_e4m3(float x) {
#if __has_builtin(__builtin_amdgcn_cvt_pk_fp8_f32)
  return (uint32_t)__builtin_amdgcn_cvt_pk_fp8_f32(x, x, 0, false) & 0xFFu;
#else
  union { float f; uint32_t u; } c; c.f = x;
  uint32_t s = (c.u >> 24) & 0x80u;
  float a = fabsf(x);
  if (!(a < 448.f)) return s | 0x7Eu;
  int e; float mf = frexpf(a, &e); (void)mf;
  e -= 1;
  int E = e < -6 ? -6 : e;
  float q = nearbyintf(ldexpf(a, 3 - E));
  int qi = (int)q;
  if (qi == 0) return s;
  while (qi >= 16) { qi >>= 1; ++E; }
  if (qi < 8) return s | (uint32_t)qi;                       // subnormal (E==-6)
  return s | ((uint32_t)(E + 7) << 3) | (uint32_t)(qi & 7);
#endif
}

__device__ __forceinline__ uint32_t f32x4_to_e4m3x4(float x, float y, float z, float w) {
#if __has_builtin(__builtin_amdgcn_cvt_pk_fp8_f32)
  int lo = __builtin_amdgcn_cvt_pk_fp8_f32(x, y, 0, false);
  return (uint32_t)__builtin_amdgcn_cvt_pk_fp8_f32(z, w, lo, true);
#else
  return f32_to_e4m3(x) | (f32_to_e4m3(y) << 8) | (f32_to_e4m3(z) << 16) | (f32_to_e4m3(w) << 24);
#endif
}

__device__ __forceinline__ long pk64(uint2 v) {
  union { uint2 u; long l; } c; c.u = v; return c.l;
}

// ---------------- Threefry2x32 (JAX-compatible), host+device ----------------
__host__ __device__ __forceinline__ void tf2x32(uint32_t k0, uint32_t k1,
                                                uint32_t x0, uint32_t x1,
                                                uint32_t &y0, uint32_t &y1) {
  const uint32_t ks2 = k0 ^ k1 ^ 0x1BD11BDAu;
  x0 += k0; x1 += k1;
#define TF_R(r) { x0 += x1; x1 = (x1 << (r)) | (x1 >> (32 - (r))); x1 ^= x0; }
  TF_R(13) TF_R(15) TF_R(26) TF_R(6)
  x0 += k1; x1 += ks2 + 1u;
  TF_R(17) TF_R(29) TF_R(16) TF_R(24)
  x0 += ks2; x1 += k0 + 2u;
  TF_R(13) TF_R(15) TF_R(26) TF_R(6)
  x0 += k0; x1 += k1 + 3u;
  TF_R(17) TF_R(29) TF_R(16) TF_R(24)
  x0 += k1; x1 += ks2 + 4u;
  TF_R(13) TF_R(15) TF_R(26) TF_R(6)
  x0 += ks2; x1 += k0 + 5u;
#undef TF_R
  y0 = x0; y1 = x1;
}

// ---------------- host-computed per-step constants ----------------
struct IdxParams {
  uint32_t k1x[NSTEP], k1y[NSTEP], k2x[NSTEP], k2y[NSTEP];
  uint32_t mult[NSTEP];
  uint32_t Msp[NSTEP], Ssp[NSTEP], Asp[NSTEP];   // magic for span = 8*T2
  uint32_t Mt2[NSTEP], St2[NSTEP], At2[NSTEP];   // magic for T2
};

// Hacker's Delight 10-9 unsigned magic
static void magicu(uint32_t d, uint32_t* M, uint32_t* s, uint32_t* a) {
  uint32_t p, nc, delta, q1, r1, q2, r2;
  *a = 0;
  nc = 0xFFFFFFFFu - (0u - d) % d;
  p = 31;
  q1 = 0x80000000u / nc; r1 = 0x80000000u - q1 * nc;
  q2 = 0x7FFFFFFFu / d;  r2 = 0x7FFFFFFFu - q2 * d;
  do {
    p = p + 1;
    if (r1 >= nc - r1) { q1 = 2*q1 + 1; r1 = 2*r1 - nc; }
    else               { q1 = 2*q1;     r1 = 2*r1; }
    if (r2 + 1 >= d - r2) {
      if (q2 >= 0x7FFFFFFFu) *a = 1;
      q2 = 2*q2 + 1; r2 = 2*r2 + 1 - d;
    } else {
      if (q2 >= 0x80000000u) *a = 1;
      q2 = 2*q2; r2 = 2*r2 + 1;
    }
    delta = d - 1 - r2;
  } while (p < 64 && (q1 < delta || (q1 == delta && r1 == 0)));
  *M = q2 + 1; *s = p - 32;
}

__device__ __forceinline__ uint32_t mdiv(uint32_t n, uint32_t M, uint32_t s, uint32_t a) {
  uint32_t q = __umulhi(n, M);
  if (a) { q = ((n - q) >> 1) + q; return q >> (s - 1); }
  return q >> s;
}

// ------------- prep: tgt-l2norm->e4m3, ctx->f16, W->f16, Sbuf zero, idx table -------------
// blocks [0,512): targets; [512,1024): ctx; [1024,1792): W; [1792,1888): zero Sbuf;
// [1888,1888+9984): index table.
__global__ __launch_bounds__(256) void prep_kernel(const IdxParams P,
                                                   const float* __restrict__ tgt,
                                                   const float* __restrict__ ctx,
                                                   const float* __restrict__ W,
                                                   uint8_t* __restrict__ tn8,
                                                   _Float16* __restrict__ ctxh,
                                                   _Float16* __restrict__ Wh,
                                                   uint16_t* __restrict__ idxTab,
                                                   float* __restrict__ Sbuf,
                                                   float* __restrict__ out) {
  const int bx = blockIdx.x;
  const int tid = threadIdx.x;
  if (bx == 0 && tid == 0) out[0] = 0.f;
  if (bx < 512) {                                        // tgt: normalize -> e4m3
    const int lane = tid & 63;
    const int row = bx * 4 + (tid >> 6);
    float4 v = ((const float4*)(tgt + (size_t)row * DD))[lane];
    float ss = v.x*v.x + v.y*v.y + v.z*v.z + v.w*v.w;
#pragma unroll
    for (int off = 1; off < 64; off <<= 1) ss += __shfl_xor(ss, off, 64);
    const float sc = 1.0f / fmaxf(sqrtf(ss), 1e-12f);
    ((uint32_t*)(tn8 + (size_t)row * DD))[lane] =
        f32x4_to_e4m3x4(v.x * sc, v.y * sc, v.z * sc, v.w * sc);
  } else if (bx < 1792) {
    const int lane = tid & 63;
    union { _Float16 h[4]; uint2 u; } o;
    if (bx < 1024) {                                     // ctx: plain convert
      const int row = (bx - 512) * 4 + (tid >> 6);
      float4 v = ((const float4*)(ctx + (size_t)row * DD))[lane];
      o.h[0] = (_Float16)v.x; o.h[1] = (_Float16)v.y;
      o.h[2] = (_Float16)v.z; o.h[3] = (_Float16)v.w;
      ((uint2*)(ctxh + (size_t)row * DD))[lane] = o.u;
    } else {                                             // W: plain convert (3072 rows)
      const int row = (bx - 1024) * 4 + (tid >> 6);
      float4 v = ((const float4*)(W + (size_t)row * DD))[lane];
      o.h[0] = (_Float16)v.x; o.h[1] = (_Float16)v.y;
      o.h[2] = (_Float16)v.z; o.h[3] = (_Float16)v.w;
      ((uint2*)(Wh + (size_t)row * DD))[lane] = o.u;
    }
  } else if (bx < 1888) {                                // zero Sbuf (12*2048 f32)
    Sbuf[(bx - 1792) * 256 + tid] = 0.f;
  } else {                                               // index table: 832 blocks per step
    const int ib = bx - 1888;                            // 0..9983
    const int si = ib / 832;                             // block-uniform -> scalar P loads
    const int step = si + 1;
    const uint32_t T2 = (uint32_t)(TT - step);
    const uint32_t nloc = (uint32_t)(ib - si * 832) * 256u + (uint32_t)tid;  // 0..212991
    const uint32_t m = nloc / 104u;                      // b*256 + t
    const uint32_t slot = nloc - m * 104u;
    const uint32_t t = m & 255u;
    const uint32_t b = m >> 8;
    uint32_t v = 0u;
    if (t < T2 && slot <= (uint32_t)NNEG) {
      if (slot == 0u) {
        v = b * TT + t + (uint32_t)step;                 // positive row
      } else {
        const uint32_t j = (b * T2 + t) * NNEG + (slot - 1u);
        uint32_t h0, h1, l0, l1;
        tf2x32(P.k1x[si], P.k1y[si], 0u, j, h0, h1);
        tf2x32(P.k2x[si], P.k2y[si], 0u, j, l0, l1);
        const uint32_t span = 8u * T2;
        const uint32_t Msp = P.Msp[si], Ssp = P.Ssp[si], Asp = P.Asp[si];
        const uint32_t hm = h0 - mdiv(h0, Msp, Ssp, Asp) * span;
        const uint32_t lm = l0 - mdiv(l0, Msp, Ssp, Asp) * span;
        const uint32_t off = hm * P.mult[si] + lm;
        const uint32_t om = off - mdiv(off, Msp, Ssp, Asp) * span;
        const uint32_t bbq = mdiv(om, P.Mt2[si], P.St2[si], P.At2[si]);
        const uint32_t tt = om - bbq * T2;
        v = bbq * TT + tt + (uint32_t)step;
      }
    }
    idxTab[(size_t)si * (2048u * 104u) + nloc] = (uint16_t)v;
  }
}

// ------------- query GEMM (MFMA f16) + bias + l2norm -> e4m3 -------------
// grid (64 m-tiles of 32 rows, 12 steps), block 256 = 4 waves.
__global__ __launch_bounds__(256) void qgemm_mfma_kernel(const _Float16* __restrict__ ctxh,
                                                         const _Float16* __restrict__ Wh,
                                                         const float* __restrict__ bias,
                                                         uint8_t* __restrict__ qn8) {
  const int mt  = blockIdx.x;           // 0..63
  const int s   = blockIdx.y;           // 0..11
  const int tid = threadIdx.x;
  const int w   = tid >> 6;
  const int lane = tid & 63;
  const int sl = lane & 15;
  const int q  = lane >> 4;
  const int m0 = mt * 32;

  const _Float16* Arow0 = ctxh + ((size_t)(m0 + sl)) * DD + q * 8;
  const _Float16* Arow1 = Arow0 + (size_t)16 * DD;
  const _Float16* Bbase = Wh + (size_t)s * DD * DD + ((size_t)(w * 64 + sl)) * DD + q * 8;

  f32x4 acc[2][4];
#pragma unroll
  for (int mi = 0; mi < 2; ++mi)
#pragma unroll
    for (int nt = 0; nt < 4; ++nt) acc[mi][nt] = f32x4{0, 0, 0, 0};

#pragma unroll
  for (int k0 = 0; k0 < 8; ++k0) {
    const f16x8 a0 = *(const f16x8*)(Arow0 + k0 * 32);
    const f16x8 a1 = *(const f16x8*)(Arow1 + k0 * 32);
#pragma unroll
    for (int nt = 0; nt < 4; ++nt) {
      const f16x8 b = *(const f16x8*)(Bbase + (size_t)nt * 16 * DD + k0 * 32);
      acc[0][nt] = __builtin_amdgcn_mfma_f32_16x16x32_f16(a0, b, acc[0][nt], 0, 0, 0);
      acc[1][nt] = __builtin_amdgcn_mfma_f32_16x16x32_f16(a1, b, acc[1][nt], 0, 0, 0);
    }
  }
  const float* bp = bias + (size_t)s * DD + w * 64 + sl;
  __shared__ float part[4][32];
#pragma unroll
  for (int mi = 0; mi < 2; ++mi) {
#pragma unroll
    for (int nt = 0; nt < 4; ++nt) {
      const float bv = bp[nt * 16];
#pragma unroll
      for (int r = 0; r < 4; ++r) acc[mi][nt][r] += bv;
    }
    float ss[4];
#pragma unroll
    for (int r = 0; r < 4; ++r) {
      float v = 0.f;
#pragma unroll
      for (int nt = 0; nt < 4; ++nt) v += acc[mi][nt][r] * acc[mi][nt][r];
      ss[r] = v;
    }
#pragma unroll
    for (int off = 1; off < 16; off <<= 1) {
#pragma unroll
      for (int r = 0; r < 4; ++r) ss[r] += __shfl_xor(ss[r], off, 64);
    }
    if (sl == 0) {
#pragma unroll
      for (int r = 0; r < 4; ++r) part[w][mi * 16 + q * 4 + r] = ss[r];
    }
  }
  __syncthreads();
#pragma unroll
  for (int mi = 0; mi < 2; ++mi) {
#pragma unroll
    for (int r = 0; r < 4; ++r) {
      const int row = q * 4 + r;
      const float tot = part[0][mi * 16 + row] + part[1][mi * 16 + row]
                      + part[2][mi * 16 + row] + part[3][mi * 16 + row];
      const float sc = 1.0f / fmaxf(sqrtf(tot), 1e-12f);
      uint8_t* outp = qn8 + (((size_t)s * (BB * TT)) + m0 + mi * 16 + row) * DD + w * 64 + sl;
#pragma unroll
      for (int nt = 0; nt < 4; ++nt)
        outp[nt * 16] = (uint8_t)f32_to_e4m3(acc[mi][nt][r] * sc);
    }
  }
}

// ------------- scoring v3: panel-dense fp8 GEMM, LDS scores, no-max softmax -------------
// grid (4 k-panels of 512, 64 q-tiles of 32, 12 steps), block 256 = 4 waves.
// All K streamed coalesced (4 rows / 1KB wave-instr); zero global gathers.
__global__ __launch_bounds__(256) void score_kernel(const uint8_t* __restrict__ qn8,
                                                    const uint8_t* __restrict__ tn8,
                                                    const uint16_t* __restrict__ idxTab,
                                                    float* __restrict__ Sbuf,
                                                    float* __restrict__ X0) {
  const int p   = blockIdx.x;           // panel 0..3 (keys p*512 .. +512)
  const int qt  = blockIdx.y;           // 0..63
  const int si  = blockIdx.z;           // 0..11
  const int step = si + 1;
  const int T2  = TT - step;
  const int b   = qt >> 3;
  const int t0  = (qt & 7) * 32;
  const int tid = threadIdx.x;
  const int w   = tid >> 6;
  const int l   = tid & 63;
  const int q16 = l & 15;
  const int kh  = l >> 4;

  __shared__ __align__(16) uint8_t  Kl[64 * 256];     // 16KB K chunk (swizzled)
  __shared__ __align__(16) uint8_t  Ql[32 * 256];     // 8KB Q tile (swizzled)
  __shared__ __align__(16) uint8_t  Sc[32 * 1024];    // 32KB scores f16 (swizzled)
  __shared__ __align__(16) uint16_t ridx[32 * SLOTP]; // 6.65KB

  // stage ridx: 32 rows x 104 u16 = 6656B (16B-aligned by construction)
  const uint16_t* gi = idxTab + ((size_t)si * 2048 + b * 256 + t0) * SLOTP;
#pragma unroll
  for (int i = tid; i < 416; i += 256)
    ((uint4*)ridx)[i] = ((const uint4*)gi)[i];

  // stage Q tile: 32 rows x 256B, coalesced, row-XOR-swizzled
  const uint8_t* qg = qn8 + ((size_t)si * 2048 + b * 256 + t0) * DD;
#pragma unroll
  for (int i = tid; i < 512; i += 256) {
    const int row = i >> 4, col = i & 15;
    uint4 v = *(const uint4*)(qg + row * 256 + col * 16);
    *(uint4*)(Ql + row * 256 + ((col * 16) ^ ((row & 7) << 4))) = v;
  }
  __syncthreads();

  // B-frags: 2 query groups x 8 k-steps, 8B each (2-way-free swizzled reads)
  uint2 qv[2][8];
#pragma unroll
  for (int qg2 = 0; qg2 < 2; ++qg2) {
    const int qr = qg2 * 16 + q16;
#pragma unroll
    for (int k0 = 0; k0 < 8; ++k0)
      qv[qg2][k0] = *(const uint2*)(Ql + qr * 256 + ((kh * 8 + k0 * 32) ^ ((qr & 7) << 4)));
  }

  // K chunks: 8 x 64 rows
  for (int c = 0; c < 8; ++c) {
    __syncthreads();                    // protect Kl from previous chunk's readers
    const uint8_t* kg = tn8 + ((size_t)p * 512 + c * 64) * DD;
#pragma unroll
    for (int i = tid; i < 1024; i += 256) {
      const int row = i >> 4, col = i & 15;
      uint4 v = *(const uint4*)(kg + row * 256 + col * 16);
      *(uint4*)(Kl + row * 256 + ((col * 16) ^ ((row & 7) << 4))) = v;
    }
    __syncthreads();

    const int krow = w * 16 + q16;      // wave w owns key-tile w of chunk
    uint2 av[8];
#pragma unroll
    for (int k0 = 0; k0 < 8; ++k0)
      av[k0] = *(const uint2*)(Kl + krow * 256 + ((kh * 8 + k0 * 32) ^ ((krow & 7) << 4)));

#pragma unroll
    for (int qg2 = 0; qg2 < 2; ++qg2) {
      f32x4 a0 = {0, 0, 0, 0}, a1 = {0, 0, 0, 0};
#pragma unroll
      for (int k0 = 0; k0 < 8; k0 += 2) {
        a0 = __builtin_amdgcn_mfma_f32_16x16x32_fp8_fp8(pk64(av[k0]),     pk64(qv[qg2][k0]),     a0, 0, 0, 0);
        a1 = __builtin_amdgcn_mfma_f32_16x16x32_fp8_fp8(pk64(av[k0 + 1]), pk64(qv[qg2][k0 + 1]), a1, 0, 0, 0);
      }
      // lane holds D[key = kh*4+r][q = q16]; write 4 f16 (8B) to Sc[q][k]
      const int qr = qg2 * 16 + q16;
      const int kk = c * 64 + w * 16 + kh * 4;
      union { _Float16 h[4]; uint2 u; } o;
#pragma unroll
      for (int r = 0; r < 4; ++r) o.h[r] = (_Float16)(a0[r] + a1[r]);
      *(uint2*)(Sc + qr * 1024 + ((kk * 2) ^ ((qr & 7) << 3))) = o.u;
    }
  }
  __syncthreads();

  // no-max partial softmax: 32 q x 8 lanes; logits <= ~10.5 so exp is f32-safe
  const int q = tid >> 3, i = tid & 7;
  const int t = t0 + q;
  float e = 0.f;
  if (t < T2) {
    for (int s = i; s <= NNEG; s += 8) {
      const int R = (int)ridx[q * SLOTP + s];
      if ((R >> 9) == p) {
        const int kl = R & 511;
        const float x = 10.0f * (float)(*(const _Float16*)(Sc + q * 1024 + ((kl * 2) ^ ((q & 7) << 3))));
        e += __expf(x);
        if (s == 0) X0[(size_t)si * 2048 + b * 256 + t] = x;
      }
    }
  }
  e += __shfl_xor(e, 1, 64);
  e += __shfl_xor(e, 2, 64);
  e += __shfl_xor(e, 4, 64);
  if (i == 0 && t < T2)
    atomicAdd(&Sbuf[si * 2048 + b * 256 + t], e);
}

// ---------------- final: loss = mean over valid q of (log S - x0), scaled ----------------
__global__ __launch_bounds__(256) void final_kernel(const float* __restrict__ Sbuf,
                                                    const float* __restrict__ X0,
                                                    float* __restrict__ out) {
  const int idx = blockIdx.x * 256 + threadIdx.x;   // 96 blocks -> 24576
  float v = 0.f;
  const int si = idx >> 11, m = idx & 2047, t = m & 255;
  const int T2 = TT - (si + 1);
  if (t < T2)
    v = (logf(Sbuf[idx]) - X0[idx]) / (12.0f * (float)(BB * T2));
#pragma unroll
  for (int off = 1; off < 64; off <<= 1) v += __shfl_xor(v, off, 64);
  __shared__ float ws[4];
  if ((threadIdx.x & 63) == 0) ws[threadIdx.x >> 6] = v;
  __syncthreads();
  if (threadIdx.x == 0)
    atomicAdd(out, ws[0] + ws[1] + ws[2] + ws[3]);
}

extern "C" void kernel_launch(void* const* d_in, const int* in_sizes, int n_in,
                              void* d_out, int out_size, void* d_ws, size_t ws_size,
                              hipStream_t stream) {
  const float* ctx  = (const float*)d_in[0];
  const float* tgt  = (const float*)d_in[1];
  const float* W    = (const float*)d_in[2];
  const float* bias = (const float*)d_in[3];
  float* out = (float*)d_out;

  uint8_t* tn8   = (uint8_t*)d_ws;                               // 512 KB
  _Float16* ctxh = (_Float16*)(tn8 + (size_t)BB * TT * DD);      // 1 MB
  _Float16* Wh   = ctxh + (size_t)BB * TT * DD;                  // 1.5 MB
  uint8_t* qn8   = (uint8_t*)(Wh + (size_t)NSTEP * DD * DD);     // 6.29 MB
  uint16_t* idxTab = (uint16_t*)(qn8 + (size_t)NSTEP * BB * TT * DD); // 5.11 MB
  float* Sbuf = (float*)(idxTab + (size_t)NSTEP * 2048 * SLOTP); // 96 KB
  float* X0   = Sbuf + (size_t)NSTEP * 2048;                     // 96 KB

  // host-side per-step constants (deterministic; same every call)
  IdxParams P;
  for (int s = 0; s < NSTEP; ++s) {
    uint32_t a, b;
    tf2x32(0u, 1234u, 0u, (uint32_t)(s + 1), a, b);              // fold_in(key(1234), step)
    uint32_t h1a, h1b, h2a, h2b;
    tf2x32(a, b, 0u, 2u, h1a, h1b);                              // split -> k1
    tf2x32(a, b, 1u, 3u, h2a, h2b);                              // split -> k2
    P.k1x[s] = h1a; P.k1y[s] = h1b; P.k2x[s] = h2a; P.k2y[s] = h2b;
    const uint32_t T2 = (uint32_t)(TT - (s + 1));
    const uint32_t span = 8u * T2;
    uint32_t m = 65536u % span;
    P.mult[s] = (uint32_t)(((uint64_t)m * m) % span);
    magicu(span, &P.Msp[s], &P.Ssp[s], &P.Asp[s]);
    magicu(T2,   &P.Mt2[s], &P.St2[s], &P.At2[s]);
  }

  hipLaunchKernelGGL(prep_kernel, dim3(1888 + 12 * 832), dim3(256), 0, stream,
                     P, tgt, ctx, W, tn8, ctxh, Wh, idxTab, Sbuf, out);
  hipLaunchKernelGGL(qgemm_mfma_kernel, dim3(64, NSTEP), dim3(256), 0, stream,
                     ctxh, Wh, bias, qn8);
  hipLaunchKernelGGL(score_kernel, dim3(4, 64, NSTEP), dim3(256), 0, stream,
                     qn8, tn8, idxTab, Sbuf, X0);
  hipLaunchKernelGGL(final_kernel, dim3(96), dim3(256), 0, stream,
                     Sbuf, X0, out);
}